// Round 8
// baseline (512.623 us; speedup 1.0000x reference)
//
#include <hip/hip_runtime.h>
#include <math.h>

// Problem constants
#define NB   8
#define CCH  256
#define PPX  2304            // 48*48
#define CPb  (CCH*PPX)       // per-batch C*P = 589824
#define NTOT (NB*CPb)        // 4718592
#define PSQ  (PPX*PPX)       // 5308416
#define PADIMG 2500          // 50*50 padded image

typedef short short8_t __attribute__((ext_vector_type(8)));
typedef float f4_t __attribute__((ext_vector_type(4)));
typedef float f16_t __attribute__((ext_vector_type(16)));

__device__ __forceinline__ float relu_(float x){ return x > 0.f ? x : 0.f; }

__device__ __forceinline__ unsigned short f2bf(float f) {
  unsigned int u = __builtin_bit_cast(unsigned int, f);
  u += 0x7fffu + ((u >> 16) & 1u);
  return (unsigned short)(u >> 16);
}
__device__ __forceinline__ float bf2f(unsigned short h) {
  unsigned int u = ((unsigned int)h) << 16;
  return __builtin_bit_cast(float, u);
}
__device__ __forceinline__ unsigned int pack2(float a, float b) {
  return (unsigned int)f2bf(a) | ((unsigned int)f2bf(b) << 16);
}

// async global -> LDS, 16B per lane, wave-uniform LDS base (lane spreads x16B)
__device__ __forceinline__ void gll16(const void* g, void* l) {
  __builtin_amdgcn_global_load_lds(
      (const __attribute__((address_space(1))) unsigned int*)g,
      (__attribute__((address_space(3))) unsigned int*)l, 16, 0, 0);
}

// ---------------------------------------------------------------------------
// small casts / repacks
// ---------------------------------------------------------------------------
__global__ __launch_bounds__(256) void castw(
    const float* __restrict__ w, unsigned short* __restrict__ o, int n)
{
  const int i = blockIdx.x * 256 + threadIdx.x;
  if (i < n) o[i] = f2bf(w[i]);
}

__global__ __launch_bounds__(256) void repack_w(
    const float* __restrict__ w, unsigned short* __restrict__ wr, int Cin)
{
  const int idx = blockIdx.x * 256 + threadIdx.x;
  const int total = 9 * 256 * Cin;
  if (idx >= total) return;
  const int c = idx % Cin;
  const int rest = idx / Cin;
  const int o = rest % 256;
  const int tap = rest / 256;
  wr[idx] = f2bf(w[((size_t)o * Cin + c) * 9 + tap]);
}

// zero only the border positions of a padded [b][2500][C] image
__global__ __launch_bounds__(64) void zero_borders(
    unsigned short* __restrict__ img, int C)
{
  const int b = blockIdx.x / 196;
  const int e = blockIdx.x % 196;
  int pos;
  if (e < 50)       pos = e;                      // row 0
  else if (e < 100) pos = 2450 + (e - 50);        // row 49
  else if (e < 148) pos = (e - 99) * 50;          // x = 0, rows 1..48
  else              pos = (e - 147) * 50 + 49;    // x = 49, rows 1..48
  const int c = threadIdx.x * 8;
  if (c < C) {
    uint4 z = {0u, 0u, 0u, 0u};
    *(uint4*)(img + ((size_t)b * PADIMG + pos) * C + c) = z;
  }
}

// ftr [b][c][p] fp32 -> x_t [b][p][c] bf16
__global__ __launch_bounds__(256) void transpose_cast(
    const float* __restrict__ ftr, unsigned short* __restrict__ xt)
{
  const int p0 = blockIdx.x * 64, c0 = blockIdx.y * 64, b = blockIdx.z;
  const int t = threadIdx.x;
  __shared__ unsigned short T[64][72];
  #pragma unroll
  for (int pass = 0; pass < 4; pass++) {
    const int cr = pass * 16 + (t >> 4);
    const int pc = (t & 15) * 4;
    float4 v = *(const float4*)&ftr[((size_t)(b * 256 + c0 + cr)) * PPX + p0 + pc];
    T[pc + 0][cr] = f2bf(v.x); T[pc + 1][cr] = f2bf(v.y);
    T[pc + 2][cr] = f2bf(v.z); T[pc + 3][cr] = f2bf(v.w);
  }
  __syncthreads();
  #pragma unroll
  for (int pass = 0; pass < 2; pass++) {
    const int pr = pass * 32 + (t >> 3);
    const int cc = (t & 7) * 8;
    *(uint4*)&xt[((size_t)(b * PPX + p0 + pr)) * 256 + c0 + cc] = *(const uint4*)&T[pr][cc];
  }
}

// ---------------------------------------------------------------------------
// Generic bf16 MFMA GEMM: O[n][m] = sum_k A[m][k]*B[n][k]
// Tile 128x128, 4 waves. Double-buffered async staging, 1 barrier per k-step.
// EPI: 0 none, 1 bias on m, 2 bias on n, 3 pv-epilogue (delta*acc+ftr -> attn_p)
// ---------------------------------------------------------------------------
template<int EPI>
__global__ __launch_bounds__(256) void gemm_nt(
    const unsigned short* __restrict__ A, long Ab,
    const unsigned short* __restrict__ B, long Bb, int K,
    unsigned short* __restrict__ O, long Ob, int ldo,
    const float* __restrict__ bias,
    const float* __restrict__ ftr, const float* __restrict__ delta, int bstart)
{
  const int t = threadIdx.x;
  const int ln = t & 63;
  const int wid = t >> 6;
  const int wm = (wid & 1) * 64, wn = (wid >> 1) * 64;
  const int lm = ln & 15, lg = ln >> 4;
  const int m0 = blockIdx.x * 128, n0 = blockIdx.y * 128;
  const long bz = blockIdx.z;
  const unsigned short* Ap = A + bz * Ab;
  const unsigned short* Bp = B + bz * Bb;

  __shared__ __align__(16) unsigned short As[2][128 * 32];
  __shared__ __align__(16) unsigned short Bs[2][128 * 32];

  const int sR = ln >> 2, sP = ln & 3;
  const int fbase = lm * 32 + (((lg + (lm >> 2)) & 3) * 8);

  f4_t acc[4][4];
  #pragma unroll
  for (int i = 0; i < 4; i++)
    #pragma unroll
    for (int j = 0; j < 4; j++) acc[i][j] = (f4_t){0.f, 0.f, 0.f, 0.f};

  const int S = K / 32;

  // prologue: stage slice 0 into buffer 0
  #pragma unroll
  for (int i = wid; i < 8; i += 4) {
    const int R = i * 16 + sR;
    const int l = (sP - (R >> 2)) & 3;
    gll16(Ap + (size_t)(m0 + R) * K + l * 8, &As[0][i * 512]);
    gll16(Bp + (size_t)(n0 + R) * K + l * 8, &Bs[0][i * 512]);
  }

  for (int s = 0; s < S; s++) {
    __syncthreads();   // slice s landed; buf[(s+1)&1] readers done
    if (s + 1 < S) {
      const int kk = (s + 1) * 32;
      #pragma unroll
      for (int i = wid; i < 8; i += 4) {
        const int R = i * 16 + sR;
        const int l = (sP - (R >> 2)) & 3;
        gll16(Ap + (size_t)(m0 + R) * K + kk + l * 8, &As[(s + 1) & 1][i * 512]);
        gll16(Bp + (size_t)(n0 + R) * K + kk + l * 8, &Bs[(s + 1) & 1][i * 512]);
      }
    }
    const unsigned short* Asb = As[s & 1];
    const unsigned short* Bsb = Bs[s & 1];
    short8_t a[4], b[4];
    #pragma unroll
    for (int ti = 0; ti < 4; ti++)
      a[ti] = *(const short8_t*)(Asb + (wm + ti * 16) * 32 + fbase);
    #pragma unroll
    for (int tj = 0; tj < 4; tj++)
      b[tj] = *(const short8_t*)(Bsb + (wn + tj * 16) * 32 + fbase);
    #pragma unroll
    for (int ti = 0; ti < 4; ti++)
      #pragma unroll
      for (int tj = 0; tj < 4; tj++)
        acc[ti][tj] = __builtin_amdgcn_mfma_f32_16x16x32_bf16(
            a[ti], b[tj], acc[ti][tj], 0, 0, 0);
  }

  if (EPI == 3) {
    const int b = bstart + (int)bz;
    const float d0 = delta[0];
    #pragma unroll
    for (int ti = 0; ti < 4; ti++) {
      const int mb = m0 + wm + ti * 16 + (lg << 2);   // channel c
      #pragma unroll
      for (int tj = 0; tj < 4; tj++) {
        const int n = n0 + wn + tj * 16 + lm;          // pixel j
        const int y = n / 48, x = n - (n / 48) * 48;
        const size_t pp = (size_t)(y + 1) * 50 + (x + 1);
        float vr[4];
        #pragma unroll
        for (int r = 0; r < 4; r++)
          vr[r] = d0 * acc[ti][tj][r] + ftr[((size_t)(b * 256 + mb + r)) * PPX + n];
        uint2 o;
        o.x = pack2(vr[0], vr[1]);
        o.y = pack2(vr[2], vr[3]);
        *(uint2*)(O + ((size_t)b * PADIMG + pp) * 256 + mb) = o;
      }
    }
  } else {
    #pragma unroll
    for (int ti = 0; ti < 4; ti++) {
      const int mb = m0 + wm + ti * 16 + (lg << 2);
      #pragma unroll
      for (int tj = 0; tj < 4; tj++) {
        const int n = n0 + wn + tj * 16 + lm;
        float add0 = 0.f, add1 = 0.f, add2 = 0.f, add3 = 0.f;
        if (EPI == 1) { add0 = bias[mb]; add1 = bias[mb+1]; add2 = bias[mb+2]; add3 = bias[mb+3]; }
        if (EPI == 2) { add0 = add1 = add2 = add3 = bias[n]; }
        uint2 o;
        o.x = pack2(acc[ti][tj][0] + add0, acc[ti][tj][1] + add1);
        o.y = pack2(acc[ti][tj][2] + add2, acc[ti][tj][3] + add3);
        *(uint2*)(O + bz * Ob + (size_t)n * ldo + mb) = o;
      }
    }
  }
}

// ---------------------------------------------------------------------------
// Row softmax of St IN PLACE: row j: W[i] = exp(s-mx)/sum  (bf16 out)
// ---------------------------------------------------------------------------
__global__ __launch_bounds__(256) void rowstats(
    unsigned short* __restrict__ St, long sstride)
{
  const int j = blockIdx.x, bb = blockIdx.y;
  unsigned short* row = St + (long)bb * sstride + (size_t)j * PPX;
  const int t = threadIdx.x;

  float v[16];
  int nv = 0;
  float m = -1e30f;
  for (int ch = t; ch < 288; ch += 256) {
    const uint4 d = *(const uint4*)(row + ch * 8);
    const unsigned int* dp = (const unsigned int*)&d;
    #pragma unroll
    for (int q = 0; q < 4; q++) {
      v[nv]     = bf2f((unsigned short)(dp[q] & 0xffffu));
      v[nv + 1] = bf2f((unsigned short)(dp[q] >> 16));
      m = fmaxf(m, fmaxf(v[nv], v[nv + 1]));
      nv += 2;
    }
  }
  __shared__ float red[256];
  red[t] = m; __syncthreads();
  for (int s = 128; s > 0; s >>= 1) {
    if (t < s) red[t] = fmaxf(red[t], red[t + s]);
    __syncthreads();
  }
  m = red[0]; __syncthreads();
  float sum = 0.f;
  for (int u = 0; u < nv; u++) { v[u] = expf(v[u] - m); sum += v[u]; }
  red[t] = sum; __syncthreads();
  for (int s = 128; s > 0; s >>= 1) {
    if (t < s) red[t] += red[t + s];
    __syncthreads();
  }
  const float inv = 1.f / red[0];
  int u = 0;
  for (int ch = t; ch < 288; ch += 256) {
    unsigned int res[4];
    #pragma unroll
    for (int q = 0; q < 4; q++) {
      res[q] = pack2(v[u] * inv, v[u + 1] * inv);
      u += 2;
    }
    *(uint4*)(row + ch * 8) = *(const uint4*)res;
  }
}

// ---------------------------------------------------------------------------
// Conv3x3 + BN + ReLU, MFMA 32x32x16 bf16, [pos][chan] activations.
// Block: 128 thr (2 waves). Block tile 64 Cout x 256 px; wave 64 Cout x 128 px.
// B (acts): LDS double-buffered (2 x 24 KB), async gll16, 1 barrier/slice.
// A (weights): direct global->VGPR fragments, pipelined one tap ahead.
// ---------------------------------------------------------------------------
template<bool OUT_BF16>
__global__ __launch_bounds__(128) void conv_mfma(
    const unsigned short* __restrict__ act_p, int Cin,
    const unsigned short* __restrict__ wr,
    const float* __restrict__ gamma, const float* __restrict__ beta,
    const float* __restrict__ mean,  const float* __restrict__ var,
    void* __restrict__ outv)
{
  const int t  = threadIdx.x;
  const int wv = t >> 6;          // wave: pixel half (128 px each)
  const int ln = t & 63;
  const int l31 = ln & 31;
  const int l5  = ln >> 5;

  const int bx = blockIdx.x;      // 72 = 8 images * 9 px-tiles(256)
  const int bb = bx / 9;
  const int p0 = (bx % 9) * 256;
  const int m0 = blockIdx.y * 64;

  __shared__ __align__(16) unsigned short Bs[2][384 * 32];   // 48 KB

  const int qbase = p0 + 2 * (p0 / 48);     // padded row of window start
  int qoff[4];
  #pragma unroll
  for (int tj = 0; tj < 4; tj++) {
    const int dp = wv * 128 + tj * 32 + l31;          // 0..255
    qoff[tj] = dp + 2 * ((p0 + dp) / 48 - p0 / 48) + 51;
  }

  const int sR4 = ln >> 2, sP = ln & 3;     // staging lane constants

  f16_t acc[2][4];
  #pragma unroll
  for (int i = 0; i < 2; i++)
    #pragma unroll
    for (int j = 0; j < 4; j++)
      #pragma unroll
      for (int r = 0; r < 16; r++) acc[i][j][r] = 0.f;

  const unsigned short* gb = act_p + (size_t)bb * PADIMG * Cin;

  // ---- helpers ----
  #define STAGE_B(buf, c0_)                                                   \
    for (int i = wv; i < 24; i += 2) {                                        \
      const int R = i * 16 + sR4;                                             \
      int Rg = qbase + R; if (Rg > PADIMG - 1) Rg = PADIMG - 1;               \
      const int l = (sP - (R >> 2)) & 3;                                      \
      gll16(gb + (size_t)Rg * Cin + (c0_) + l * 8, &Bs[buf][i * 512]);        \
    }
  #define LOAD_A(dst, tap_, c0_)                                              \
    _Pragma("unroll")                                                         \
    for (int ti = 0; ti < 2; ti++)                                            \
      _Pragma("unroll")                                                       \
      for (int kh = 0; kh < 2; kh++)                                          \
        dst[ti][kh] = *(const short8_t*)(wr +                                 \
            ((size_t)((tap_) * 256 + m0 + ti * 32 + l31)) * Cin +             \
            (c0_) + kh * 16 + l5 * 8);

  short8_t acur[2][2], anext[2][2];

  // prologue
  STAGE_B(0, 0);
  LOAD_A(acur, 0, 0);

  const int S = Cin / 32;
  for (int s = 0; s < S; s++) {
    __syncthreads();             // slice s staged; other buf's readers done
    const int c0 = s * 32;
    if (s + 1 < S) { STAGE_B((s + 1) & 1, c0 + 32); }
    const unsigned short* Bsb = Bs[s & 1];
    #pragma unroll
    for (int tap = 0; tap < 9; tap++) {
      if (tap < 8) { LOAD_A(anext, tap + 1, c0); }
      else if (s + 1 < S) { LOAD_A(anext, 0, c0 + 32); }
      const int off = (tap / 3 - 1) * 50 + (tap % 3 - 1);
      #pragma unroll
      for (int kh = 0; kh < 2; kh++) {
        #pragma unroll
        for (int tj = 0; tj < 4; tj++) {
          const int R = qoff[tj] + off;
          // logical chan-group g=(kh<<1)|l5 lives at physical slot (g+(R>>2))&3
          const int slot = ((((kh << 1) | l5)) + (R >> 2)) & 3;
          const short8_t bfr = *(const short8_t*)(Bsb + R * 32 + slot * 8);
          acc[0][tj] = __builtin_amdgcn_mfma_f32_32x32x16_bf16(
              acur[0][kh], bfr, acc[0][tj], 0, 0, 0);
          acc[1][tj] = __builtin_amdgcn_mfma_f32_32x32x16_bf16(
              acur[1][kh], bfr, acc[1][tj], 0, 0, 0);
        }
      }
      #pragma unroll
      for (int ti = 0; ti < 2; ti++)
        #pragma unroll
        for (int kh = 0; kh < 2; kh++) acur[ti][kh] = anext[ti][kh];
    }
  }
  #undef STAGE_B
  #undef LOAD_A

  // ---- epilogue: BN + ReLU. C/D: col(px)=l31, row(m)=8g+4*l5+r (g=reg>>2) ----
  #pragma unroll
  for (int ti = 0; ti < 2; ti++) {
    #pragma unroll
    for (int g = 0; g < 4; g++) {
      const int mq = m0 + ti * 32 + 8 * g + 4 * l5;
      float inv[4], add[4];
      #pragma unroll
      for (int r = 0; r < 4; r++) {
        inv[r] = gamma[mq + r] * rsqrtf(var[mq + r] + 1e-5f);
        add[r] = beta[mq + r] - mean[mq + r] * inv[r];
      }
      #pragma unroll
      for (int tj = 0; tj < 4; tj++) {
        const int p = p0 + wv * 128 + tj * 32 + l31;
        float vr[4];
        #pragma unroll
        for (int r = 0; r < 4; r++)
          vr[r] = relu_(acc[ti][tj][4 * g + r] * inv[r] + add[r]);
        if (OUT_BF16) {
          uint2 o;
          o.x = pack2(vr[0], vr[1]);
          o.y = pack2(vr[2], vr[3]);
          *(uint2*)((unsigned short*)outv + ((size_t)(bb * PPX + p)) * 256 + mq) = o;
        } else {
          #pragma unroll
          for (int r = 0; r < 4; r++)
            ((float*)outv)[((size_t)(bb * 256 + mq + r)) * PPX + p] = vr[r];
        }
      }
    }
  }
}

// ---------------------------------------------------------------------------
// pool3(avg/max of xt bf16) * sigmoid(act1) -> padded bf16 cat [pos][512]
// ---------------------------------------------------------------------------
__global__ __launch_bounds__(256) void pool_gate_cat(
    const unsigned short* __restrict__ xt, const unsigned short* __restrict__ act1b,
    unsigned short* __restrict__ cat_p)
{
  const int idx = blockIdx.x * 256 + threadIdx.x;   // < NTOT
  const int c = idx & 255;
  const int rest = idx >> 8;
  const int p = rest % PPX;
  const int b = rest / PPX;
  const int y = p / 48, x = p - (p / 48) * 48;
  const unsigned short* base = xt + ((size_t)b * PPX) * 256 + c;
  float s = 0.f, mxv = -1e30f;
  #pragma unroll
  for (int dy = -1; dy <= 1; dy++) {
    const int yy = y + dy;
    if (yy < 0 || yy >= 48) continue;
    #pragma unroll
    for (int dx = -1; dx <= 1; dx++) {
      const int xx = x + dx;
      if (xx < 0 || xx >= 48) continue;
      const float f = bf2f(base[(size_t)(yy * 48 + xx) * 256]);
      s += f; mxv = fmaxf(mxv, f);
    }
  }
  const float g = bf2f(act1b[(size_t)idx]);
  const float gate = 1.f / (1.f + expf(-g));
  const size_t pp = (size_t)(y + 1) * 50 + (x + 1);
  unsigned short* crow = cat_p + ((size_t)b * PADIMG + pp) * 512;
  crow[c]       = f2bf(mxv * gate);
  crow[c + 256] = f2bf(s * (1.f / 9.f) * gate);
}

// ---------------------------------------------------------------------------
extern "C" void kernel_launch(void* const* d_in, const int* in_sizes, int n_in,
                              void* d_out, int out_size, void* d_ws, size_t ws_size,
                              hipStream_t stream)
{
  const float* ftr  = (const float*)d_in[0];
  const float* wq   = (const float*)d_in[1];
  const float* bq   = (const float*)d_in[2];
  const float* wk   = (const float*)d_in[3];
  const float* bk   = (const float*)d_in[4];
  const float* wv   = (const float*)d_in[5];
  const float* bv   = (const float*)d_in[6];
  const float* delta= (const float*)d_in[7];
  const float* w1   = (const float*)d_in[8];
  const float* g1   = (const float*)d_in[9];
  const float* b1   = (const float*)d_in[10];
  const float* m1   = (const float*)d_in[11];
  const float* v1   = (const float*)d_in[12];
  const float* w2   = (const float*)d_in[13];
  const float* g2   = (const float*)d_in[14];
  const float* b2   = (const float*)d_in[15];
  const float* m2   = (const float*)d_in[16];
  const float* v2   = (const float*)d_in[17];
  float* out = (float*)d_out;

  // ---- workspace layout (shorts) ----
  const size_t XT = (size_t)NTOT;
  unsigned short* base = (unsigned short*)d_ws;
  unsigned short* xt   = base;
  unsigned short* qt   = xt  + XT;
  unsigned short* kt   = qt  + XT;
  unsigned short* vbuf = kt  + XT;
  unsigned short* wqb  = vbuf + XT;
  unsigned short* wkb  = wqb + 65536;
  unsigned short* wvb  = wkb + 65536;
  unsigned short* wr1  = wvb + 65536;
  unsigned short* wr2  = wr1 + (size_t)9 * 256 * 256;
  unsigned short* attn_p = wr2 + (size_t)9 * 256 * 512;        // [b][2500][256]
  unsigned short* act1b  = attn_p + (size_t)NB * PADIMG * 256; // [b][2304][256]
  unsigned short* cat_p  = act1b + XT;                         // [b][2500][512]
  unsigned short* St     = cat_p + (size_t)NB * PADIMG * 512;

  const size_t head_bytes = (size_t)((char*)St - (char*)base);
  const bool modeA = ws_size >= head_bytes + (size_t)NB * PSQ * 2;

  // ---- weight preps ----
  castw<<<dim3(256), 256, 0, stream>>>(wq, wqb, 65536);
  castw<<<dim3(256), 256, 0, stream>>>(wk, wkb, 65536);
  castw<<<dim3(256), 256, 0, stream>>>(wv, wvb, 65536);
  repack_w<<<dim3((9 * 256 * 256 + 255) / 256), 256, 0, stream>>>(w1, wr1, 256);
  repack_w<<<dim3((9 * 256 * 512 + 255) / 256), 256, 0, stream>>>(w2, wr2, 512);

  // ---- border zeroing (replaces full-image memsets) ----
  zero_borders<<<dim3(NB * 196), 64, 0, stream>>>(attn_p, 256);
  zero_borders<<<dim3(NB * 196), 64, 0, stream>>>(cat_p, 512);

  // ---- x transpose ----
  transpose_cast<<<dim3(36, 4, 8), 256, 0, stream>>>(ftr, xt);

  // ---- QKV ----
  gemm_nt<1><<<dim3(2, 18, 8), 256, 0, stream>>>(
      wqb, 0L, xt, (long)CPb, 256, qt, (long)CPb, 256, bq, nullptr, nullptr, 0);
  gemm_nt<1><<<dim3(2, 18, 8), 256, 0, stream>>>(
      wkb, 0L, xt, (long)CPb, 256, kt, (long)CPb, 256, bk, nullptr, nullptr, 0);
  gemm_nt<2><<<dim3(18, 2, 8), 256, 0, stream>>>(
      xt, (long)CPb, wvb, 0L, 256, vbuf, (long)CPb, PPX, bv, nullptr, nullptr, 0);

  if (modeA) {
    gemm_nt<0><<<dim3(18, 18, 8), 256, 0, stream>>>(
        qt, (long)CPb, kt, (long)CPb, 256, St, (long)PSQ, PPX, nullptr, nullptr, nullptr, 0);
    rowstats<<<dim3(PPX, 8), 256, 0, stream>>>(St, (long)PSQ);
    gemm_nt<3><<<dim3(2, 18, 8), 256, 0, stream>>>(
        vbuf, (long)CPb, St, (long)PSQ, PPX, attn_p, 0L, 0, nullptr, ftr, delta, 0);
  } else {
    for (int b = 0; b < NB; b++) {
      gemm_nt<0><<<dim3(18, 18, 1), 256, 0, stream>>>(
          qt + (size_t)b * CPb, 0L, kt + (size_t)b * CPb, 0L, 256,
          St, 0L, PPX, nullptr, nullptr, nullptr, 0);
      rowstats<<<dim3(PPX, 1), 256, 0, stream>>>(St, 0L);
      gemm_nt<3><<<dim3(2, 18, 1), 256, 0, stream>>>(
          vbuf + (size_t)b * CPb, 0L, St, 0L, PPX, attn_p, 0L, 0, nullptr, ftr, delta, b);
    }
  }

  // ---- conv1 + BN + ReLU -> bf16 act1b [p][c] ----
  conv_mfma<true><<<dim3(72, 4), 128, 0, stream>>>(
      attn_p, 256, wr1, g1, b1, m1, v1, (void*)act1b);

  // ---- pool + gate + concat -> padded bf16 cat [pos][512] ----
  pool_gate_cat<<<dim3(NTOT / 256), 256, 0, stream>>>(xt, act1b, cat_p);

  // ---- conv2 + BN + ReLU -> fp32 out ----
  conv_mfma<false><<<dim3(72, 4), 128, 0, stream>>>(
      cat_p, 512, wr2, g2, b2, m2, v2, (void*)out);
}

// Round 9
// 474.890 us; speedup vs baseline: 1.0795x; 1.0795x over previous
//
#include <hip/hip_runtime.h>
#include <math.h>

// Problem constants
#define NB   8
#define CCH  256
#define PPX  2304            // 48*48
#define CPb  (CCH*PPX)       // per-batch C*P = 589824
#define NTOT (NB*CPb)        // 4718592
#define PSQ  (PPX*PPX)       // 5308416
#define PADIMG 2500          // 50*50 padded image

typedef short short8_t __attribute__((ext_vector_type(8)));
typedef float f4_t __attribute__((ext_vector_type(4)));

__device__ __forceinline__ float relu_(float x){ return x > 0.f ? x : 0.f; }

__device__ __forceinline__ unsigned short f2bf(float f) {
  unsigned int u = __builtin_bit_cast(unsigned int, f);
  u += 0x7fffu + ((u >> 16) & 1u);
  return (unsigned short)(u >> 16);
}
__device__ __forceinline__ float bf2f(unsigned short h) {
  unsigned int u = ((unsigned int)h) << 16;
  return __builtin_bit_cast(float, u);
}
__device__ __forceinline__ unsigned int pack2(float a, float b) {
  return (unsigned int)f2bf(a) | ((unsigned int)f2bf(b) << 16);
}

// async global -> LDS, 16B per lane, wave-uniform LDS base (lane spreads x16B)
__device__ __forceinline__ void gll16(const void* g, void* l) {
  __builtin_amdgcn_global_load_lds(
      (const __attribute__((address_space(1))) unsigned int*)g,
      (__attribute__((address_space(3))) unsigned int*)l, 16, 0, 0);
}

// ---------------------------------------------------------------------------
// small casts / repacks
// ---------------------------------------------------------------------------
__global__ __launch_bounds__(256) void castw(
    const float* __restrict__ w, unsigned short* __restrict__ o, int n)
{
  const int i = blockIdx.x * 256 + threadIdx.x;
  if (i < n) o[i] = f2bf(w[i]);
}

__global__ __launch_bounds__(256) void repack_w(
    const float* __restrict__ w, unsigned short* __restrict__ wr, int Cin)
{
  const int idx = blockIdx.x * 256 + threadIdx.x;
  const int total = 9 * 256 * Cin;
  if (idx >= total) return;
  const int c = idx % Cin;
  const int rest = idx / Cin;
  const int o = rest % 256;
  const int tap = rest / 256;
  wr[idx] = f2bf(w[((size_t)o * Cin + c) * 9 + tap]);
}

// zero only the border positions of a padded [b][2500][C] image
__global__ __launch_bounds__(64) void zero_borders(
    unsigned short* __restrict__ img, int C)
{
  const int b = blockIdx.x / 196;
  const int e = blockIdx.x % 196;
  int pos;
  if (e < 50)       pos = e;                      // row 0
  else if (e < 100) pos = 2450 + (e - 50);        // row 49
  else if (e < 148) pos = (e - 99) * 50;          // x = 0, rows 1..48
  else              pos = (e - 147) * 50 + 49;    // x = 49, rows 1..48
  const int c = threadIdx.x * 8;
  if (c < C) {
    uint4 z = {0u, 0u, 0u, 0u};
    *(uint4*)(img + ((size_t)b * PADIMG + pos) * C + c) = z;
  }
}

// ftr [b][c][p] fp32 -> x_t [b][p][c] bf16
__global__ __launch_bounds__(256) void transpose_cast(
    const float* __restrict__ ftr, unsigned short* __restrict__ xt)
{
  const int p0 = blockIdx.x * 64, c0 = blockIdx.y * 64, b = blockIdx.z;
  const int t = threadIdx.x;
  __shared__ unsigned short T[64][72];
  #pragma unroll
  for (int pass = 0; pass < 4; pass++) {
    const int cr = pass * 16 + (t >> 4);
    const int pc = (t & 15) * 4;
    float4 v = *(const float4*)&ftr[((size_t)(b * 256 + c0 + cr)) * PPX + p0 + pc];
    T[pc + 0][cr] = f2bf(v.x); T[pc + 1][cr] = f2bf(v.y);
    T[pc + 2][cr] = f2bf(v.z); T[pc + 3][cr] = f2bf(v.w);
  }
  __syncthreads();
  #pragma unroll
  for (int pass = 0; pass < 2; pass++) {
    const int pr = pass * 32 + (t >> 3);
    const int cc = (t & 7) * 8;
    *(uint4*)&xt[((size_t)(b * PPX + p0 + pr)) * 256 + c0 + cc] = *(const uint4*)&T[pr][cc];
  }
}

// ---------------------------------------------------------------------------
// Generic bf16 MFMA GEMM: O[n][m] = sum_k A[m][k]*B[n][k]
// Tile 128x128, 4 waves. Double-buffered async staging, 1 barrier per k-step.
// EPI: 0 none, 1 bias on m, 2 bias on n, 3 pv-epilogue (delta*acc+ftr -> attn_p)
// ---------------------------------------------------------------------------
template<int EPI>
__global__ __launch_bounds__(256) void gemm_nt(
    const unsigned short* __restrict__ A, long Ab,
    const unsigned short* __restrict__ B, long Bb, int K,
    unsigned short* __restrict__ O, long Ob, int ldo,
    const float* __restrict__ bias,
    const float* __restrict__ ftr, const float* __restrict__ delta, int bstart)
{
  const int t = threadIdx.x;
  const int ln = t & 63;
  const int wid = t >> 6;
  const int wm = (wid & 1) * 64, wn = (wid >> 1) * 64;
  const int lm = ln & 15, lg = ln >> 4;
  const int m0 = blockIdx.x * 128, n0 = blockIdx.y * 128;
  const long bz = blockIdx.z;
  const unsigned short* Ap = A + bz * Ab;
  const unsigned short* Bp = B + bz * Bb;

  __shared__ __align__(16) unsigned short As[2][128 * 32];
  __shared__ __align__(16) unsigned short Bs[2][128 * 32];

  const int sR = ln >> 2, sP = ln & 3;
  const int fbase = lm * 32 + (((lg + (lm >> 2)) & 3) * 8);

  f4_t acc[4][4];
  #pragma unroll
  for (int i = 0; i < 4; i++)
    #pragma unroll
    for (int j = 0; j < 4; j++) acc[i][j] = (f4_t){0.f, 0.f, 0.f, 0.f};

  const int S = K / 32;

  // prologue: stage slice 0 into buffer 0
  #pragma unroll
  for (int i = wid; i < 8; i += 4) {
    const int R = i * 16 + sR;
    const int l = (sP - (R >> 2)) & 3;
    gll16(Ap + (size_t)(m0 + R) * K + l * 8, &As[0][i * 512]);
    gll16(Bp + (size_t)(n0 + R) * K + l * 8, &Bs[0][i * 512]);
  }

  for (int s = 0; s < S; s++) {
    __syncthreads();   // slice s landed; buf[(s+1)&1] readers done
    if (s + 1 < S) {
      const int kk = (s + 1) * 32;
      #pragma unroll
      for (int i = wid; i < 8; i += 4) {
        const int R = i * 16 + sR;
        const int l = (sP - (R >> 2)) & 3;
        gll16(Ap + (size_t)(m0 + R) * K + kk + l * 8, &As[(s + 1) & 1][i * 512]);
        gll16(Bp + (size_t)(n0 + R) * K + kk + l * 8, &Bs[(s + 1) & 1][i * 512]);
      }
    }
    const unsigned short* Asb = As[s & 1];
    const unsigned short* Bsb = Bs[s & 1];
    short8_t a[4], b[4];
    #pragma unroll
    for (int ti = 0; ti < 4; ti++)
      a[ti] = *(const short8_t*)(Asb + (wm + ti * 16) * 32 + fbase);
    #pragma unroll
    for (int tj = 0; tj < 4; tj++)
      b[tj] = *(const short8_t*)(Bsb + (wn + tj * 16) * 32 + fbase);
    #pragma unroll
    for (int ti = 0; ti < 4; ti++)
      #pragma unroll
      for (int tj = 0; tj < 4; tj++)
        acc[ti][tj] = __builtin_amdgcn_mfma_f32_16x16x32_bf16(
            a[ti], b[tj], acc[ti][tj], 0, 0, 0);
  }

  if (EPI == 3) {
    const int b = bstart + (int)bz;
    const float d0 = delta[0];
    #pragma unroll
    for (int ti = 0; ti < 4; ti++) {
      const int mb = m0 + wm + ti * 16 + (lg << 2);   // channel c
      #pragma unroll
      for (int tj = 0; tj < 4; tj++) {
        const int n = n0 + wn + tj * 16 + lm;          // pixel j
        const int y = n / 48, x = n - (n / 48) * 48;
        const size_t pp = (size_t)(y + 1) * 50 + (x + 1);
        float vr[4];
        #pragma unroll
        for (int r = 0; r < 4; r++)
          vr[r] = d0 * acc[ti][tj][r] + ftr[((size_t)(b * 256 + mb + r)) * PPX + n];
        uint2 o;
        o.x = pack2(vr[0], vr[1]);
        o.y = pack2(vr[2], vr[3]);
        *(uint2*)(O + ((size_t)b * PADIMG + pp) * 256 + mb) = o;
      }
    }
  } else {
    #pragma unroll
    for (int ti = 0; ti < 4; ti++) {
      const int mb = m0 + wm + ti * 16 + (lg << 2);
      #pragma unroll
      for (int tj = 0; tj < 4; tj++) {
        const int n = n0 + wn + tj * 16 + lm;
        float add0 = 0.f, add1 = 0.f, add2 = 0.f, add3 = 0.f;
        if (EPI == 1) { add0 = bias[mb]; add1 = bias[mb+1]; add2 = bias[mb+2]; add3 = bias[mb+3]; }
        if (EPI == 2) { add0 = add1 = add2 = add3 = bias[n]; }
        uint2 o;
        o.x = pack2(acc[ti][tj][0] + add0, acc[ti][tj][1] + add1);
        o.y = pack2(acc[ti][tj][2] + add2, acc[ti][tj][3] + add3);
        *(uint2*)(O + bz * Ob + (size_t)n * ldo + mb) = o;
      }
    }
  }
}

// ---------------------------------------------------------------------------
// Row softmax of St IN PLACE: row j: W[i] = exp(s-mx)/sum  (bf16 out)
// ---------------------------------------------------------------------------
__global__ __launch_bounds__(256) void rowstats(
    unsigned short* __restrict__ St, long sstride)
{
  const int j = blockIdx.x, bb = blockIdx.y;
  unsigned short* row = St + (long)bb * sstride + (size_t)j * PPX;
  const int t = threadIdx.x;

  float v[16];
  int nv = 0;
  float m = -1e30f;
  for (int ch = t; ch < 288; ch += 256) {
    const uint4 d = *(const uint4*)(row + ch * 8);
    const unsigned int* dp = (const unsigned int*)&d;
    #pragma unroll
    for (int q = 0; q < 4; q++) {
      v[nv]     = bf2f((unsigned short)(dp[q] & 0xffffu));
      v[nv + 1] = bf2f((unsigned short)(dp[q] >> 16));
      m = fmaxf(m, fmaxf(v[nv], v[nv + 1]));
      nv += 2;
    }
  }
  __shared__ float red[256];
  red[t] = m; __syncthreads();
  for (int s = 128; s > 0; s >>= 1) {
    if (t < s) red[t] = fmaxf(red[t], red[t + s]);
    __syncthreads();
  }
  m = red[0]; __syncthreads();
  float sum = 0.f;
  for (int u = 0; u < nv; u++) { v[u] = expf(v[u] - m); sum += v[u]; }
  red[t] = sum; __syncthreads();
  for (int s = 128; s > 0; s >>= 1) {
    if (t < s) red[t] += red[t + s];
    __syncthreads();
  }
  const float inv = 1.f / red[0];
  int u = 0;
  for (int ch = t; ch < 288; ch += 256) {
    unsigned int res[4];
    #pragma unroll
    for (int q = 0; q < 4; q++) {
      res[q] = pack2(v[u] * inv, v[u + 1] * inv);
      u += 2;
    }
    *(uint4*)(row + ch * 8) = *(const uint4*)res;
  }
}

// ---------------------------------------------------------------------------
// Conv3x3 partial (split-K over Cin), MFMA 16x16x32 bf16, [pos][chan] acts.
// r5 structure: 128 thr (2 waves), tile 64 Cout x 128 px, all-LDS async
// staging, 2 barriers per 32-chan slice. blockIdx.z = K-split (2 halves).
// Writes raw fp32 partials part[z][b*PPX+p][256] (float4/lane).
// ---------------------------------------------------------------------------
__global__ __launch_bounds__(128) void conv_part(
    const unsigned short* __restrict__ act_p, int Cin,
    const unsigned short* __restrict__ wr,
    float* __restrict__ part)
{
  const int t  = threadIdx.x;
  const int wv = t >> 6;
  const int ln = t & 63;
  const int lm = ln & 15;
  const int lg = ln >> 4;

  const int bx = blockIdx.x;      // 144 = 8 images * 18 pixel-tiles
  const int bb = bx / 18;
  const int p0 = (bx % 18) * 128;
  const int m0 = blockIdx.y * 64;
  const int zz = blockIdx.z;      // K-split
  const int c_start = zz * (Cin >> 1);

  __shared__ __align__(16) unsigned short Bs[240 * 32];    // [pos][c] 15.4 KB
  __shared__ __align__(16) unsigned short As[9 * 64 * 32]; // [tap][m][c] 36.9 KB

  const int qbase = p0 + 2 * (p0 / 48);
  int qoff[4];
  #pragma unroll
  for (int tj = 0; tj < 4; tj++) {
    const int p = p0 + wv * 64 + tj * 16 + lm;
    qoff[tj] = (p - p0) + 2 * (p / 48 - p0 / 48) + 51;
  }

  const int sR = ln >> 2, sP = ln & 3;
  const int abase = lm * 32 + (((lg + (lm >> 2)) & 3) * 8);

  f4_t acc[4][4];
  #pragma unroll
  for (int i = 0; i < 4; i++)
    #pragma unroll
    for (int j = 0; j < 4; j++) acc[i][j] = (f4_t){0.f, 0.f, 0.f, 0.f};

  const int cend = c_start + (Cin >> 1);
  for (int c0 = c_start; c0 < cend; c0 += 32) {
    __syncthreads();
    // ---- stage B: 240 pos x 32 chans, 15 async instructions ----
    const unsigned short* gb = act_p + ((size_t)bb * PADIMG) * Cin + c0;
    for (int i = wv; i < 15; i += 2) {
      const int R = i * 16 + sR;
      int Rg = qbase + R;
      if (Rg > PADIMG - 1) Rg = PADIMG - 1;              // clamp tail OOB
      const int l = (sP - (R >> 2)) & 3;
      gll16(gb + (size_t)Rg * Cin + l * 8, Bs + i * 512);
    }
    // ---- stage A: 9 taps x 64 m x 32 chans, 36 async instructions ----
    for (int i = wv; i < 36; i += 2) {
      const int R = i * 16 + sR;                          // 0..575
      const int tap = R >> 6, mr = R & 63;
      const int l = (sP - (R >> 2)) & 3;
      gll16(wr + ((size_t)(tap * 256 + m0 + mr)) * Cin + c0 + l * 8, As + i * 512);
    }
    __syncthreads();
    // ---- compute: 9 taps, 16 MFMA each ----
    #pragma unroll
    for (int ky = 0; ky < 3; ky++) {
      #pragma unroll
      for (int kx = 0; kx < 3; kx++) {
        const int off = (ky - 1) * 50 + (kx - 1);
        const int tap = ky * 3 + kx;
        short8_t a[4], b[4];
        #pragma unroll
        for (int ti = 0; ti < 4; ti++)
          a[ti] = *(const short8_t*)(As + tap * 2048 + ti * 512 + abase);
        #pragma unroll
        for (int tj = 0; tj < 4; tj++) {
          const int R = qoff[tj] + off;
          const int slot = (lg + (R >> 2)) & 3;
          b[tj] = *(const short8_t*)(Bs + R * 32 + slot * 8);
        }
        #pragma unroll
        for (int ti = 0; ti < 4; ti++)
          #pragma unroll
          for (int tj = 0; tj < 4; tj++)
            acc[ti][tj] = __builtin_amdgcn_mfma_f32_16x16x32_bf16(
                a[ti], b[tj], acc[ti][tj], 0, 0, 0);
      }
    }
  }

  // ---- epilogue: raw fp32 partial store (float4 per lane) ----
  float* pb = part + (size_t)zz * NB * PPX * 256;
  #pragma unroll
  for (int ti = 0; ti < 4; ti++) {
    const int m = m0 + ti * 16 + (lg << 2);
    #pragma unroll
    for (int tj = 0; tj < 4; tj++) {
      const int p = p0 + wv * 64 + tj * 16 + lm;
      *(f4_t*)(pb + ((size_t)(bb * PPX + p)) * 256 + m) = acc[ti][tj];
    }
  }
}

// ---------------------------------------------------------------------------
// combine partials + BN + ReLU -> bf16 [b*PPX+p][256]  (conv1 output)
// ---------------------------------------------------------------------------
__global__ __launch_bounds__(256) void combine_pc(
    const float* __restrict__ part,
    const float* __restrict__ gamma, const float* __restrict__ beta,
    const float* __restrict__ mean,  const float* __restrict__ var,
    unsigned short* __restrict__ outb)
{
  const size_t idx = (size_t)blockIdx.x * 256 + threadIdx.x;
  const int c = (int)(idx & 255);
  const float v = part[idx] + part[(size_t)NB * PPX * 256 + idx];
  const float inv = gamma[c] * rsqrtf(var[c] + 1e-5f);
  const float add = beta[c] - mean[c] * inv;
  outb[idx] = f2bf(relu_(v * inv + add));
}

// ---------------------------------------------------------------------------
// combine partials + BN + ReLU -> fp32 [b][c][p] via LDS transpose (conv2 out)
// ---------------------------------------------------------------------------
__global__ __launch_bounds__(256) void combine_cp(
    const float* __restrict__ part,
    const float* __restrict__ gamma, const float* __restrict__ beta,
    const float* __restrict__ mean,  const float* __restrict__ var,
    float* __restrict__ out)
{
  const int p0 = blockIdx.x * 64, c0 = blockIdx.y * 64, b = blockIdx.z;
  const int t = threadIdx.x;
  __shared__ float T[64][68];
  const size_t poff = (size_t)NB * PPX * 256;
  #pragma unroll
  for (int pass = 0; pass < 4; pass++) {
    const int pr = pass * 16 + (t >> 4);
    const int cc = (t & 15) * 4;
    const size_t row = ((size_t)(b * PPX + p0 + pr)) * 256 + c0 + cc;
    const float4 v0 = *(const float4*)(part + row);
    const float4 v1 = *(const float4*)(part + poff + row);
    const float vs[4] = {v0.x + v1.x, v0.y + v1.y, v0.z + v1.z, v0.w + v1.w};
    #pragma unroll
    for (int i = 0; i < 4; i++) {
      const int c = c0 + cc + i;
      const float inv = gamma[c] * rsqrtf(var[c] + 1e-5f);
      const float add = beta[c] - mean[c] * inv;
      T[cc + i][pr] = relu_(vs[i] * inv + add);
    }
  }
  __syncthreads();
  #pragma unroll
  for (int pass = 0; pass < 4; pass++) {
    const int cr = pass * 16 + (t >> 4);
    const int pc = (t & 15) * 4;
    *(float4*)&out[((size_t)(b * 256 + c0 + cr)) * PPX + p0 + pc] =
        *(const float4*)&T[cr][pc];
  }
}

// ---------------------------------------------------------------------------
// pool3(avg/max of xt bf16) * sigmoid(act1) -> padded bf16 cat [pos][512]
// ---------------------------------------------------------------------------
__global__ __launch_bounds__(256) void pool_gate_cat(
    const unsigned short* __restrict__ xt, const unsigned short* __restrict__ act1b,
    unsigned short* __restrict__ cat_p)
{
  const int idx = blockIdx.x * 256 + threadIdx.x;   // < NTOT
  const int c = idx & 255;
  const int rest = idx >> 8;
  const int p = rest % PPX;
  const int b = rest / PPX;
  const int y = p / 48, x = p - (p / 48) * 48;
  const unsigned short* base = xt + ((size_t)b * PPX) * 256 + c;
  float s = 0.f, mxv = -1e30f;
  #pragma unroll
  for (int dy = -1; dy <= 1; dy++) {
    const int yy = y + dy;
    if (yy < 0 || yy >= 48) continue;
    #pragma unroll
    for (int dx = -1; dx <= 1; dx++) {
      const int xx = x + dx;
      if (xx < 0 || xx >= 48) continue;
      const float f = bf2f(base[(size_t)(yy * 48 + xx) * 256]);
      s += f; mxv = fmaxf(mxv, f);
    }
  }
  const float g = bf2f(act1b[(size_t)idx]);
  const float gate = 1.f / (1.f + expf(-g));
  const size_t pp = (size_t)(y + 1) * 50 + (x + 1);
  unsigned short* crow = cat_p + ((size_t)b * PADIMG + pp) * 512;
  crow[c]       = f2bf(mxv * gate);
  crow[c + 256] = f2bf(s * (1.f / 9.f) * gate);
}

// ---------------------------------------------------------------------------
extern "C" void kernel_launch(void* const* d_in, const int* in_sizes, int n_in,
                              void* d_out, int out_size, void* d_ws, size_t ws_size,
                              hipStream_t stream)
{
  const float* ftr  = (const float*)d_in[0];
  const float* wq   = (const float*)d_in[1];
  const float* bq   = (const float*)d_in[2];
  const float* wk   = (const float*)d_in[3];
  const float* bk   = (const float*)d_in[4];
  const float* wv   = (const float*)d_in[5];
  const float* bv   = (const float*)d_in[6];
  const float* delta= (const float*)d_in[7];
  const float* w1   = (const float*)d_in[8];
  const float* g1   = (const float*)d_in[9];
  const float* b1   = (const float*)d_in[10];
  const float* m1   = (const float*)d_in[11];
  const float* v1   = (const float*)d_in[12];
  const float* w2   = (const float*)d_in[13];
  const float* g2   = (const float*)d_in[14];
  const float* b2   = (const float*)d_in[15];
  const float* m2   = (const float*)d_in[16];
  const float* v2   = (const float*)d_in[17];
  float* out = (float*)d_out;

  // ---- workspace layout (shorts) ----
  const size_t XT = (size_t)NTOT;
  unsigned short* base = (unsigned short*)d_ws;
  unsigned short* xt   = base;
  unsigned short* qt   = xt  + XT;
  unsigned short* kt   = qt  + XT;
  unsigned short* vbuf = kt  + XT;
  unsigned short* wqb  = vbuf + XT;
  unsigned short* wkb  = wqb + 65536;
  unsigned short* wvb  = wkb + 65536;
  unsigned short* wr1  = wvb + 65536;
  unsigned short* wr2  = wr1 + (size_t)9 * 256 * 256;
  unsigned short* attn_p = wr2 + (size_t)9 * 256 * 512;        // [b][2500][256]
  unsigned short* act1b  = attn_p + (size_t)NB * PADIMG * 256; // [b][2304][256]
  unsigned short* cat_p  = act1b + XT;                         // [b][2500][512]
  float* part = (float*)(cat_p + (size_t)NB * PADIMG * 512);   // [2][b*PPX+p][256] fp32
  unsigned short* St     = (unsigned short*)(part + (size_t)2 * NB * PPX * 256);

  const size_t head_bytes = (size_t)((char*)St - (char*)base);
  const bool modeA = ws_size >= head_bytes + (size_t)NB * PSQ * 2;

  // ---- weight preps ----
  castw<<<dim3(256), 256, 0, stream>>>(wq, wqb, 65536);
  castw<<<dim3(256), 256, 0, stream>>>(wk, wkb, 65536);
  castw<<<dim3(256), 256, 0, stream>>>(wv, wvb, 65536);
  repack_w<<<dim3((9 * 256 * 256 + 255) / 256), 256, 0, stream>>>(w1, wr1, 256);
  repack_w<<<dim3((9 * 256 * 512 + 255) / 256), 256, 0, stream>>>(w2, wr2, 512);

  // ---- border zeroing ----
  zero_borders<<<dim3(NB * 196), 64, 0, stream>>>(attn_p, 256);
  zero_borders<<<dim3(NB * 196), 64, 0, stream>>>(cat_p, 512);

  // ---- x transpose ----
  transpose_cast<<<dim3(36, 4, 8), 256, 0, stream>>>(ftr, xt);

  // ---- QKV ----
  gemm_nt<1><<<dim3(2, 18, 8), 256, 0, stream>>>(
      wqb, 0L, xt, (long)CPb, 256, qt, (long)CPb, 256, bq, nullptr, nullptr, 0);
  gemm_nt<1><<<dim3(2, 18, 8), 256, 0, stream>>>(
      wkb, 0L, xt, (long)CPb, 256, kt, (long)CPb, 256, bk, nullptr, nullptr, 0);
  gemm_nt<2><<<dim3(18, 2, 8), 256, 0, stream>>>(
      xt, (long)CPb, wvb, 0L, 256, vbuf, (long)CPb, PPX, bv, nullptr, nullptr, 0);

  if (modeA) {
    gemm_nt<0><<<dim3(18, 18, 8), 256, 0, stream>>>(
        qt, (long)CPb, kt, (long)CPb, 256, St, (long)PSQ, PPX, nullptr, nullptr, nullptr, 0);
    rowstats<<<dim3(PPX, 8), 256, 0, stream>>>(St, (long)PSQ);
    gemm_nt<3><<<dim3(2, 18, 8), 256, 0, stream>>>(
        vbuf, (long)CPb, St, (long)PSQ, PPX, attn_p, 0L, 0, nullptr, ftr, delta, 0);
  } else {
    for (int b = 0; b < NB; b++) {
      gemm_nt<0><<<dim3(18, 18, 1), 256, 0, stream>>>(
          qt + (size_t)b * CPb, 0L, kt + (size_t)b * CPb, 0L, 256,
          St, 0L, PPX, nullptr, nullptr, nullptr, 0);
      rowstats<<<dim3(PPX, 1), 256, 0, stream>>>(St, 0L);
      gemm_nt<3><<<dim3(2, 18, 1), 256, 0, stream>>>(
          vbuf + (size_t)b * CPb, 0L, St, 0L, PPX, attn_p, 0L, 0, nullptr, ftr, delta, b);
    }
  }

  // ---- conv1 (split-K=2) -> partials -> combine -> bf16 act1b [p][c] ----
  conv_part<<<dim3(144, 4, 2), 128, 0, stream>>>(attn_p, 256, wr1, part);
  combine_pc<<<dim3(NTOT / 256), 256, 0, stream>>>(part, g1, b1, m1, v1, act1b);

  // ---- pool + gate + concat -> padded bf16 cat [pos][512] ----
  pool_gate_cat<<<dim3(NTOT / 256), 256, 0, stream>>>(xt, act1b, cat_p);

  // ---- conv2 (split-K=2) -> partials -> combine -> fp32 out [b][c][p] ----
  conv_part<<<dim3(144, 4, 2), 128, 0, stream>>>(cat_p, 512, wr2, part);
  combine_cp<<<dim3(36, 4, 8), 256, 0, stream>>>(part, g2, b2, m2, v2, out);
}

// Round 10
// 463.033 us; speedup vs baseline: 1.1071x; 1.0256x over previous
//
#include <hip/hip_runtime.h>
#include <math.h>

// Problem constants
#define NB   8
#define CCH  256
#define PPX  2304            // 48*48
#define CPb  (CCH*PPX)       // per-batch C*P = 589824
#define NTOT (NB*CPb)        // 4718592
#define PSQ  (PPX*PPX)       // 5308416
#define PADIMG 2500          // 50*50 padded image

typedef short short8_t __attribute__((ext_vector_type(8)));
typedef float f4_t __attribute__((ext_vector_type(4)));

__device__ __forceinline__ float relu_(float x){ return x > 0.f ? x : 0.f; }

__device__ __forceinline__ unsigned short f2bf(float f) {
  unsigned int u = __builtin_bit_cast(unsigned int, f);
  u += 0x7fffu + ((u >> 16) & 1u);
  return (unsigned short)(u >> 16);
}
__device__ __forceinline__ float bf2f(unsigned short h) {
  unsigned int u = ((unsigned int)h) << 16;
  return __builtin_bit_cast(float, u);
}
__device__ __forceinline__ unsigned int pack2(float a, float b) {
  return (unsigned int)f2bf(a) | ((unsigned int)f2bf(b) << 16);
}

// async global -> LDS, 16B per lane, wave-uniform LDS base (lane spreads x16B)
__device__ __forceinline__ void gll16(const void* g, void* l) {
  __builtin_amdgcn_global_load_lds(
      (const __attribute__((address_space(1))) unsigned int*)g,
      (__attribute__((address_space(3))) unsigned int*)l, 16, 0, 0);
}

// ---------------------------------------------------------------------------
// small casts / repacks
// ---------------------------------------------------------------------------
__global__ __launch_bounds__(256) void castw(
    const float* __restrict__ w, unsigned short* __restrict__ o, int n)
{
  const int i = blockIdx.x * 256 + threadIdx.x;
  if (i < n) o[i] = f2bf(w[i]);
}

__global__ __launch_bounds__(256) void repack_w(
    const float* __restrict__ w, unsigned short* __restrict__ wr, int Cin)
{
  const int idx = blockIdx.x * 256 + threadIdx.x;
  const int total = 9 * 256 * Cin;
  if (idx >= total) return;
  const int c = idx % Cin;
  const int rest = idx / Cin;
  const int o = rest % 256;
  const int tap = rest / 256;
  wr[idx] = f2bf(w[((size_t)o * Cin + c) * 9 + tap]);
}

// zero only the border positions of a padded [b][2500][C] image
__global__ __launch_bounds__(64) void zero_borders(
    unsigned short* __restrict__ img, int C)
{
  const int b = blockIdx.x / 196;
  const int e = blockIdx.x % 196;
  int pos;
  if (e < 50)       pos = e;                      // row 0
  else if (e < 100) pos = 2450 + (e - 50);        // row 49
  else if (e < 148) pos = (e - 99) * 50;          // x = 0, rows 1..48
  else              pos = (e - 147) * 50 + 49;    // x = 49, rows 1..48
  const int c = threadIdx.x * 8;
  if (c < C) {
    uint4 z = {0u, 0u, 0u, 0u};
    *(uint4*)(img + ((size_t)b * PADIMG + pos) * C + c) = z;
  }
}

// ftr [b][c][p] fp32 -> x_t [b][p][c] bf16
__global__ __launch_bounds__(256) void transpose_cast(
    const float* __restrict__ ftr, unsigned short* __restrict__ xt)
{
  const int p0 = blockIdx.x * 64, c0 = blockIdx.y * 64, b = blockIdx.z;
  const int t = threadIdx.x;
  __shared__ unsigned short T[64][72];
  #pragma unroll
  for (int pass = 0; pass < 4; pass++) {
    const int cr = pass * 16 + (t >> 4);
    const int pc = (t & 15) * 4;
    float4 v = *(const float4*)&ftr[((size_t)(b * 256 + c0 + cr)) * PPX + p0 + pc];
    T[pc + 0][cr] = f2bf(v.x); T[pc + 1][cr] = f2bf(v.y);
    T[pc + 2][cr] = f2bf(v.z); T[pc + 3][cr] = f2bf(v.w);
  }
  __syncthreads();
  #pragma unroll
  for (int pass = 0; pass < 2; pass++) {
    const int pr = pass * 32 + (t >> 3);
    const int cc = (t & 7) * 8;
    *(uint4*)&xt[((size_t)(b * PPX + p0 + pr)) * 256 + c0 + cc] = *(const uint4*)&T[pr][cc];
  }
}

// ---------------------------------------------------------------------------
// Generic bf16 MFMA GEMM: O[n][m] = sum_k A[m][k]*B[n][k]
// Tile 128x128, 4 waves. Double-buffered async staging, 1 barrier per k-step.
// 1-D grid with XCD-affinity decode: bz = blockIdx.x & (2^bzl - 1) so all
// blocks of one image land on one XCD (8 XCDs, round-robin by block id).
// EPI: 0 none, 1 bias on m, 2 bias on n, 3 pv-epilogue (delta*acc+ftr -> attn_p)
// ---------------------------------------------------------------------------
template<int EPI>
__global__ __launch_bounds__(256) void gemm_nt(
    const unsigned short* __restrict__ A, long Ab,
    const unsigned short* __restrict__ B, long Bb, int K,
    unsigned short* __restrict__ O, long Ob, int ldo,
    const float* __restrict__ bias,
    const float* __restrict__ ftr, const float* __restrict__ delta, int bstart,
    int gx, int bzl)
{
  const int t = threadIdx.x;
  const int ln = t & 63;
  const int wid = t >> 6;
  const int wm = (wid & 1) * 64, wn = (wid >> 1) * 64;
  const int lm = ln & 15, lg = ln >> 4;

  const int id = blockIdx.x;
  const long bz = id & ((1 << bzl) - 1);     // image -> XCD affinity
  const int r  = id >> bzl;
  const int m0 = (r % gx) * 128, n0 = (r / gx) * 128;

  const unsigned short* Ap = A + bz * Ab;
  const unsigned short* Bp = B + bz * Bb;

  __shared__ __align__(16) unsigned short As[2][128 * 32];
  __shared__ __align__(16) unsigned short Bs[2][128 * 32];

  const int sR = ln >> 2, sP = ln & 3;
  const int fbase = lm * 32 + (((lg + (lm >> 2)) & 3) * 8);

  f4_t acc[4][4];
  #pragma unroll
  for (int i = 0; i < 4; i++)
    #pragma unroll
    for (int j = 0; j < 4; j++) acc[i][j] = (f4_t){0.f, 0.f, 0.f, 0.f};

  const int S = K / 32;

  // prologue: stage slice 0 into buffer 0
  #pragma unroll
  for (int i = wid; i < 8; i += 4) {
    const int R = i * 16 + sR;
    const int l = (sP - (R >> 2)) & 3;
    gll16(Ap + (size_t)(m0 + R) * K + l * 8, &As[0][i * 512]);
    gll16(Bp + (size_t)(n0 + R) * K + l * 8, &Bs[0][i * 512]);
  }

  for (int s = 0; s < S; s++) {
    __syncthreads();   // slice s landed; buf[(s+1)&1] readers done
    if (s + 1 < S) {
      const int kk = (s + 1) * 32;
      #pragma unroll
      for (int i = wid; i < 8; i += 4) {
        const int R = i * 16 + sR;
        const int l = (sP - (R >> 2)) & 3;
        gll16(Ap + (size_t)(m0 + R) * K + kk + l * 8, &As[(s + 1) & 1][i * 512]);
        gll16(Bp + (size_t)(n0 + R) * K + kk + l * 8, &Bs[(s + 1) & 1][i * 512]);
      }
    }
    const unsigned short* Asb = As[s & 1];
    const unsigned short* Bsb = Bs[s & 1];
    short8_t a[4], b[4];
    #pragma unroll
    for (int ti = 0; ti < 4; ti++)
      a[ti] = *(const short8_t*)(Asb + (wm + ti * 16) * 32 + fbase);
    #pragma unroll
    for (int tj = 0; tj < 4; tj++)
      b[tj] = *(const short8_t*)(Bsb + (wn + tj * 16) * 32 + fbase);
    #pragma unroll
    for (int ti = 0; ti < 4; ti++)
      #pragma unroll
      for (int tj = 0; tj < 4; tj++)
        acc[ti][tj] = __builtin_amdgcn_mfma_f32_16x16x32_bf16(
            a[ti], b[tj], acc[ti][tj], 0, 0, 0);
  }

  if (EPI == 3) {
    const int b = bstart + (int)bz;
    const float d0 = delta[0];
    #pragma unroll
    for (int ti = 0; ti < 4; ti++) {
      const int mb = m0 + wm + ti * 16 + (lg << 2);   // channel c
      #pragma unroll
      for (int tj = 0; tj < 4; tj++) {
        const int n = n0 + wn + tj * 16 + lm;          // pixel j
        const int y = n / 48, x = n - (n / 48) * 48;
        const size_t pp = (size_t)(y + 1) * 50 + (x + 1);
        float vr[4];
        #pragma unroll
        for (int r2 = 0; r2 < 4; r2++)
          vr[r2] = d0 * acc[ti][tj][r2] + ftr[((size_t)(b * 256 + mb + r2)) * PPX + n];
        uint2 o;
        o.x = pack2(vr[0], vr[1]);
        o.y = pack2(vr[2], vr[3]);
        *(uint2*)(O + ((size_t)b * PADIMG + pp) * 256 + mb) = o;
      }
    }
  } else {
    #pragma unroll
    for (int ti = 0; ti < 4; ti++) {
      const int mb = m0 + wm + ti * 16 + (lg << 2);
      #pragma unroll
      for (int tj = 0; tj < 4; tj++) {
        const int n = n0 + wn + tj * 16 + lm;
        float add0 = 0.f, add1 = 0.f, add2 = 0.f, add3 = 0.f;
        if (EPI == 1) { add0 = bias[mb]; add1 = bias[mb+1]; add2 = bias[mb+2]; add3 = bias[mb+3]; }
        if (EPI == 2) { add0 = add1 = add2 = add3 = bias[n]; }
        uint2 o;
        o.x = pack2(acc[ti][tj][0] + add0, acc[ti][tj][1] + add1);
        o.y = pack2(acc[ti][tj][2] + add2, acc[ti][tj][3] + add3);
        *(uint2*)(O + bz * Ob + (size_t)n * ldo + mb) = o;
      }
    }
  }
}

// ---------------------------------------------------------------------------
// Row softmax of St IN PLACE: row j: W[i] = exp(s-mx)/sum  (bf16 out)
// ---------------------------------------------------------------------------
__global__ __launch_bounds__(256) void rowstats(
    unsigned short* __restrict__ St, long sstride)
{
  const int j = blockIdx.x, bb = blockIdx.y;
  unsigned short* row = St + (long)bb * sstride + (size_t)j * PPX;
  const int t = threadIdx.x;

  float v[16];
  int nv = 0;
  float m = -1e30f;
  for (int ch = t; ch < 288; ch += 256) {
    const uint4 d = *(const uint4*)(row + ch * 8);
    const unsigned int* dp = (const unsigned int*)&d;
    #pragma unroll
    for (int q = 0; q < 4; q++) {
      v[nv]     = bf2f((unsigned short)(dp[q] & 0xffffu));
      v[nv + 1] = bf2f((unsigned short)(dp[q] >> 16));
      m = fmaxf(m, fmaxf(v[nv], v[nv + 1]));
      nv += 2;
    }
  }
  __shared__ float red[256];
  red[t] = m; __syncthreads();
  for (int s = 128; s > 0; s >>= 1) {
    if (t < s) red[t] = fmaxf(red[t], red[t + s]);
    __syncthreads();
  }
  m = red[0]; __syncthreads();
  float sum = 0.f;
  for (int u = 0; u < nv; u++) { v[u] = expf(v[u] - m); sum += v[u]; }
  red[t] = sum; __syncthreads();
  for (int s = 128; s > 0; s >>= 1) {
    if (t < s) red[t] += red[t + s];
    __syncthreads();
  }
  const float inv = 1.f / red[0];
  int u = 0;
  for (int ch = t; ch < 288; ch += 256) {
    unsigned int res[4];
    #pragma unroll
    for (int q = 0; q < 4; q++) {
      res[q] = pack2(v[u] * inv, v[u + 1] * inv);
      u += 2;
    }
    *(uint4*)(row + ch * 8) = *(const uint4*)res;
  }
}

// ---------------------------------------------------------------------------
// Conv3x3 partial (split-K over Cin), MFMA 16x16x32 bf16, [pos][chan] acts.
// 1-D grid 1152 with XCD-affinity: bb = id & 7 (image -> XCD).
// 128 thr (2 waves), tile 64 Cout x 128 px, all-LDS async staging.
// Writes raw fp32 partials part[z][b*PPX+p][256].
// ---------------------------------------------------------------------------
__global__ __launch_bounds__(128) void conv_part(
    const unsigned short* __restrict__ act_p, int Cin,
    const unsigned short* __restrict__ wr,
    float* __restrict__ part)
{
  const int t  = threadIdx.x;
  const int wv = t >> 6;
  const int ln = t & 63;
  const int lm = ln & 15;
  const int lg = ln >> 4;

  // decode 1152 = 8 images (XCD) x 18 px-tiles x 4 m-tiles x 2 k-splits
  const int id = blockIdx.x;
  const int bb = id & 7;
  int r = id >> 3;
  const int p0 = (r % 18) * 128; r /= 18;
  const int m0 = (r & 3) * 64;
  const int zz = r >> 2;
  const int c_start = zz * (Cin >> 1);

  __shared__ __align__(16) unsigned short Bs[240 * 32];    // [pos][c] 15.4 KB
  __shared__ __align__(16) unsigned short As[9 * 64 * 32]; // [tap][m][c] 36.9 KB

  const int qbase = p0 + 2 * (p0 / 48);
  int qoff[4];
  #pragma unroll
  for (int tj = 0; tj < 4; tj++) {
    const int p = p0 + wv * 64 + tj * 16 + lm;
    qoff[tj] = (p - p0) + 2 * (p / 48 - p0 / 48) + 51;
  }

  const int sR = ln >> 2, sP = ln & 3;
  const int abase = lm * 32 + (((lg + (lm >> 2)) & 3) * 8);

  f4_t acc[4][4];
  #pragma unroll
  for (int i = 0; i < 4; i++)
    #pragma unroll
    for (int j = 0; j < 4; j++) acc[i][j] = (f4_t){0.f, 0.f, 0.f, 0.f};

  const int cend = c_start + (Cin >> 1);
  for (int c0 = c_start; c0 < cend; c0 += 32) {
    __syncthreads();
    // ---- stage B: 240 pos x 32 chans, 15 async instructions ----
    const unsigned short* gb = act_p + ((size_t)bb * PADIMG) * Cin + c0;
    for (int i = wv; i < 15; i += 2) {
      const int R = i * 16 + sR;
      int Rg = qbase + R;
      if (Rg > PADIMG - 1) Rg = PADIMG - 1;              // clamp tail OOB
      const int l = (sP - (R >> 2)) & 3;
      gll16(gb + (size_t)Rg * Cin + l * 8, Bs + i * 512);
    }
    // ---- stage A: 9 taps x 64 m x 32 chans, 36 async instructions ----
    for (int i = wv; i < 36; i += 2) {
      const int R = i * 16 + sR;                          // 0..575
      const int tap = R >> 6, mr = R & 63;
      const int l = (sP - (R >> 2)) & 3;
      gll16(wr + ((size_t)(tap * 256 + m0 + mr)) * Cin + c0 + l * 8, As + i * 512);
    }
    __syncthreads();
    // ---- compute: 9 taps, 16 MFMA each ----
    #pragma unroll
    for (int ky = 0; ky < 3; ky++) {
      #pragma unroll
      for (int kx = 0; kx < 3; kx++) {
        const int off = (ky - 1) * 50 + (kx - 1);
        const int tap = ky * 3 + kx;
        short8_t a[4], b[4];
        #pragma unroll
        for (int ti = 0; ti < 4; ti++)
          a[ti] = *(const short8_t*)(As + tap * 2048 + ti * 512 + abase);
        #pragma unroll
        for (int tj = 0; tj < 4; tj++) {
          const int R = qoff[tj] + off;
          const int slot = (lg + (R >> 2)) & 3;
          b[tj] = *(const short8_t*)(Bs + R * 32 + slot * 8);
        }
        #pragma unroll
        for (int ti = 0; ti < 4; ti++)
          #pragma unroll
          for (int tj = 0; tj < 4; tj++)
            acc[ti][tj] = __builtin_amdgcn_mfma_f32_16x16x32_bf16(
                a[ti], b[tj], acc[ti][tj], 0, 0, 0);
      }
    }
  }

  // ---- epilogue: raw fp32 partial store (float4 per lane) ----
  float* pb = part + (size_t)zz * NB * PPX * 256;
  #pragma unroll
  for (int ti = 0; ti < 4; ti++) {
    const int m = m0 + ti * 16 + (lg << 2);
    #pragma unroll
    for (int tj = 0; tj < 4; tj++) {
      const int p = p0 + wv * 64 + tj * 16 + lm;
      *(f4_t*)(pb + ((size_t)(bb * PPX + p)) * 256 + m) = acc[ti][tj];
    }
  }
}

// ---------------------------------------------------------------------------
// combine partials + BN + ReLU -> bf16 [b*PPX+p][256]  (conv1 output)
// ---------------------------------------------------------------------------
__global__ __launch_bounds__(256) void combine_pc(
    const float* __restrict__ part,
    const float* __restrict__ gamma, const float* __restrict__ beta,
    const float* __restrict__ mean,  const float* __restrict__ var,
    unsigned short* __restrict__ outb)
{
  const size_t idx = (size_t)blockIdx.x * 256 + threadIdx.x;
  const int c = (int)(idx & 255);
  const float v = part[idx] + part[(size_t)NB * PPX * 256 + idx];
  const float inv = gamma[c] * rsqrtf(var[c] + 1e-5f);
  const float add = beta[c] - mean[c] * inv;
  outb[idx] = f2bf(relu_(v * inv + add));
}

// ---------------------------------------------------------------------------
// combine partials + BN + ReLU -> fp32 [b][c][p] via LDS transpose (conv2 out)
// ---------------------------------------------------------------------------
__global__ __launch_bounds__(256) void combine_cp(
    const float* __restrict__ part,
    const float* __restrict__ gamma, const float* __restrict__ beta,
    const float* __restrict__ mean,  const float* __restrict__ var,
    float* __restrict__ out)
{
  const int p0 = blockIdx.x * 64, c0 = blockIdx.y * 64, b = blockIdx.z;
  const int t = threadIdx.x;
  __shared__ float T[64][68];
  const size_t poff = (size_t)NB * PPX * 256;
  #pragma unroll
  for (int pass = 0; pass < 4; pass++) {
    const int pr = pass * 16 + (t >> 4);
    const int cc = (t & 15) * 4;
    const size_t row = ((size_t)(b * PPX + p0 + pr)) * 256 + c0 + cc;
    const float4 v0 = *(const float4*)(part + row);
    const float4 v1 = *(const float4*)(part + poff + row);
    const float vs[4] = {v0.x + v1.x, v0.y + v1.y, v0.z + v1.z, v0.w + v1.w};
    #pragma unroll
    for (int i = 0; i < 4; i++) {
      const int c = c0 + cc + i;
      const float inv = gamma[c] * rsqrtf(var[c] + 1e-5f);
      const float add = beta[c] - mean[c] * inv;
      T[cc + i][pr] = relu_(vs[i] * inv + add);
    }
  }
  __syncthreads();
  #pragma unroll
  for (int pass = 0; pass < 4; pass++) {
    const int cr = pass * 16 + (t >> 4);
    const int pc = (t & 15) * 4;
    *(float4*)&out[((size_t)(b * 256 + c0 + cr)) * PPX + p0 + pc] =
        *(const float4*)&T[cr][pc];
  }
}

// ---------------------------------------------------------------------------
// pool3(avg/max of xt bf16) * sigmoid(act1) -> padded bf16 cat [pos][512]
// ---------------------------------------------------------------------------
__global__ __launch_bounds__(256) void pool_gate_cat(
    const unsigned short* __restrict__ xt, const unsigned short* __restrict__ act1b,
    unsigned short* __restrict__ cat_p)
{
  const int idx = blockIdx.x * 256 + threadIdx.x;   // < NTOT
  const int c = idx & 255;
  const int rest = idx >> 8;
  const int p = rest % PPX;
  const int b = rest / PPX;
  const int y = p / 48, x = p - (p / 48) * 48;
  const unsigned short* base = xt + ((size_t)b * PPX) * 256 + c;
  float s = 0.f, mxv = -1e30f;
  #pragma unroll
  for (int dy = -1; dy <= 1; dy++) {
    const int yy = y + dy;
    if (yy < 0 || yy >= 48) continue;
    #pragma unroll
    for (int dx = -1; dx <= 1; dx++) {
      const int xx = x + dx;
      if (xx < 0 || xx >= 48) continue;
      const float f = bf2f(base[(size_t)(yy * 48 + xx) * 256]);
      s += f; mxv = fmaxf(mxv, f);
    }
  }
  const float g = bf2f(act1b[(size_t)idx]);
  const float gate = 1.f / (1.f + expf(-g));
  const size_t pp = (size_t)(y + 1) * 50 + (x + 1);
  unsigned short* crow = cat_p + ((size_t)b * PADIMG + pp) * 512;
  crow[c]       = f2bf(mxv * gate);
  crow[c + 256] = f2bf(s * (1.f / 9.f) * gate);
}

// ---------------------------------------------------------------------------
extern "C" void kernel_launch(void* const* d_in, const int* in_sizes, int n_in,
                              void* d_out, int out_size, void* d_ws, size_t ws_size,
                              hipStream_t stream)
{
  const float* ftr  = (const float*)d_in[0];
  const float* wq   = (const float*)d_in[1];
  const float* bq   = (const float*)d_in[2];
  const float* wk   = (const float*)d_in[3];
  const float* bk   = (const float*)d_in[4];
  const float* wv   = (const float*)d_in[5];
  const float* bv   = (const float*)d_in[6];
  const float* delta= (const float*)d_in[7];
  const float* w1   = (const float*)d_in[8];
  const float* g1   = (const float*)d_in[9];
  const float* b1   = (const float*)d_in[10];
  const float* m1   = (const float*)d_in[11];
  const float* v1   = (const float*)d_in[12];
  const float* w2   = (const float*)d_in[13];
  const float* g2   = (const float*)d_in[14];
  const float* b2   = (const float*)d_in[15];
  const float* m2   = (const float*)d_in[16];
  const float* v2   = (const float*)d_in[17];
  float* out = (float*)d_out;

  // ---- workspace layout (shorts) ----
  const size_t XT = (size_t)NTOT;
  unsigned short* base = (unsigned short*)d_ws;
  unsigned short* xt   = base;
  unsigned short* qt   = xt  + XT;
  unsigned short* kt   = qt  + XT;
  unsigned short* vbuf = kt  + XT;
  unsigned short* wqb  = vbuf + XT;
  unsigned short* wkb  = wqb + 65536;
  unsigned short* wvb  = wkb + 65536;
  unsigned short* wr1  = wvb + 65536;
  unsigned short* wr2  = wr1 + (size_t)9 * 256 * 256;
  unsigned short* attn_p = wr2 + (size_t)9 * 256 * 512;        // [b][2500][256]
  unsigned short* act1b  = attn_p + (size_t)NB * PADIMG * 256; // [b][2304][256]
  unsigned short* cat_p  = act1b + XT;                         // [b][2500][512]
  float* part = (float*)(cat_p + (size_t)NB * PADIMG * 512);   // [2][b*PPX+p][256] fp32
  unsigned short* St     = (unsigned short*)(part + (size_t)2 * NB * PPX * 256);

  const size_t head_bytes = (size_t)((char*)St - (char*)base);
  const bool modeA = ws_size >= head_bytes + (size_t)NB * PSQ * 2;

  // ---- weight preps ----
  castw<<<dim3(256), 256, 0, stream>>>(wq, wqb, 65536);
  castw<<<dim3(256), 256, 0, stream>>>(wk, wkb, 65536);
  castw<<<dim3(256), 256, 0, stream>>>(wv, wvb, 65536);
  repack_w<<<dim3((9 * 256 * 256 + 255) / 256), 256, 0, stream>>>(w1, wr1, 256);
  repack_w<<<dim3((9 * 256 * 512 + 255) / 256), 256, 0, stream>>>(w2, wr2, 512);

  // ---- border zeroing ----
  zero_borders<<<dim3(NB * 196), 64, 0, stream>>>(attn_p, 256);
  zero_borders<<<dim3(NB * 196), 64, 0, stream>>>(cat_p, 512);

  // ---- x transpose ----
  transpose_cast<<<dim3(36, 4, 8), 256, 0, stream>>>(ftr, xt);

  // ---- QKV (1-D grids, image = id & 7 -> XCD affinity) ----
  gemm_nt<1><<<dim3(2 * 18 * 8), 256, 0, stream>>>(
      wqb, 0L, xt, (long)CPb, 256, qt, (long)CPb, 256, bq, nullptr, nullptr, 0, 2, 3);
  gemm_nt<1><<<dim3(2 * 18 * 8), 256, 0, stream>>>(
      wkb, 0L, xt, (long)CPb, 256, kt, (long)CPb, 256, bk, nullptr, nullptr, 0, 2, 3);
  gemm_nt<2><<<dim3(18 * 2 * 8), 256, 0, stream>>>(
      xt, (long)CPb, wvb, 0L, 256, vbuf, (long)CPb, PPX, bv, nullptr, nullptr, 0, 18, 3);

  if (modeA) {
    gemm_nt<0><<<dim3(18 * 18 * 8), 256, 0, stream>>>(
        qt, (long)CPb, kt, (long)CPb, 256, St, (long)PSQ, PPX,
        nullptr, nullptr, nullptr, 0, 18, 3);
    rowstats<<<dim3(PPX, 8), 256, 0, stream>>>(St, (long)PSQ);
    gemm_nt<3><<<dim3(2 * 18 * 8), 256, 0, stream>>>(
        vbuf, (long)CPb, St, (long)PSQ, PPX, attn_p, 0L, 0,
        nullptr, ftr, delta, 0, 2, 3);
  } else {
    for (int b = 0; b < NB; b++) {
      gemm_nt<0><<<dim3(18 * 18), 256, 0, stream>>>(
          qt + (size_t)b * CPb, 0L, kt + (size_t)b * CPb, 0L, 256,
          St, 0L, PPX, nullptr, nullptr, nullptr, 0, 18, 0);
      rowstats<<<dim3(PPX, 1), 256, 0, stream>>>(St, 0L);
      gemm_nt<3><<<dim3(2 * 18), 256, 0, stream>>>(
          vbuf + (size_t)b * CPb, 0L, St, 0L, PPX, attn_p, 0L, 0,
          nullptr, ftr, delta, b, 2, 0);
    }
  }

  // ---- conv1 (split-K=2, XCD-affine) -> partials -> combine -> bf16 act1b ----
  conv_part<<<dim3(1152), 128, 0, stream>>>(attn_p, 256, wr1, part);
  combine_pc<<<dim3(NTOT / 256), 256, 0, stream>>>(part, g1, b1, m1, v1, act1b);

  // ---- pool + gate + concat -> padded bf16 cat [pos][512] ----
  pool_gate_cat<<<dim3(NTOT / 256), 256, 0, stream>>>(xt, act1b, cat_p);

  // ---- conv2 (split-K=2, XCD-affine) -> partials -> combine -> fp32 out ----
  conv_part<<<dim3(1152), 128, 0, stream>>>(cat_p, 512, wr2, part);
  combine_cp<<<dim3(36, 4, 8), 256, 0, stream>>>(part, g2, b2, m2, v2, out);
}